// Round 5
// baseline (178.121 us; speedup 1.0000x reference)
//
#include <hip/hip_runtime.h>

// ShiftLayer: out[b,t,c] = in[b, t+off[c], c], off per c%3 = {0: identity, 1: t-1, 2: t+1},
// zero padding at t boundaries. B=8, L=8192, C=384 (divisible by 3), fp32 in/out.
//
// v6: LDS-tiled. Evidence so far: high TLP is mandatory (v1/v5 ~51us beat all
// t-coarsened variants ~60-66us), but v1/v5 still run at only ~3 TB/s HBM-side
// with idle pipes. Remaining suspect: per-CU L1/vmem front-end request traffic
// (v1 pushes 400 MB of requests for 152 MB of HBM traffic = 13 B/cy/CU > the
// 6.3 TB/s copy's 10.2). v6 stages each input line ONCE per block into LDS
// (10 rows = 15 KB), then 3 outputs/thread from LDS. Request traffic drops to
// 223 MB total; 8 blocks/CU resident preserves v1's cross-block TLP so the
// barrier latency is hidden. All addresses linear: stage at rowbase-96+s,
// compute reads lds[j], lds[j+96], lds[j+192], store at obase[j] -- no divides.

constexpr int kB = 8;
constexpr int kL = 8192;
constexpr int kC = 384;
constexpr int kV = 4;                    // fp32 elements per 16B vector
constexpr int kCV = kC / kV;             // 96 vectors per (b,t) row
constexpr int kTB = 8;                   // output rows per block
constexpr int kRows = kTB + 2;           // staged rows (with halo)
constexpr int kStage = kRows * kCV;      // 960 staged vectors = 15360 B
constexpr int kThreads = 256;
constexpr int kBlocks = kB * (kL / kTB); // 8192

typedef __attribute__((ext_vector_type(4))) float f32x4;

__global__ __launch_bounds__(256) void ShiftLayer_66932770341347_kernel(
    const f32x4* __restrict__ in, f32x4* __restrict__ out) {
  __shared__ f32x4 lds[kStage];

  int tb = blockIdx.x % (kL / kTB);      // t-tile index
  int b = blockIdx.x / (kL / kTB);       // batch
  long rowbase = (long)(tb * kTB) * kCV; // t0 * 96

  const f32x4* __restrict__ base = in + (long)b * (kL * kCV);
  f32x4* __restrict__ obase = out + (long)b * (kL * kCV) + rowbase;

  const f32x4 zero = {0.f, 0.f, 0.f, 0.f};

  // Stage rows t0-1 .. t0+8 (global vector index g = rowbase - 96 + s).
  // 4 independent coalesced load streams per thread; out-of-range slots
  // (only in the first/last t-tile) become zeros.
#pragma unroll
  for (int k = 0; k < 4; ++k) {
    int s = threadIdx.x + k * kThreads;
    if (s < kStage) {                    // threads 192..255 skip the 4th slot
      long g = rowbase - kCV + s;
      f32x4 val = zero;
      if (g >= 0 && g < (long)kL * kCV) val = base[g];
      lds[s] = val;
    }
  }
  __syncthreads();

  // 3 outputs per thread. Output j reads prev=lds[j], cur=lds[j+96],
  // next=lds[j+192]; store address obase + j (contiguous per wave).
  // Base channel of output j: c0 = 4*(j%96); c0%3 == j%3 (96%3==0, 4==1 mod 3),
  // and j%3 = (tid%3 + k)%3 since 256 == 1 mod 3.
  int m0 = threadIdx.x % 3;
#pragma unroll
  for (int k = 0; k < 3; ++k) {
    int j = threadIdx.x + k * kThreads;
    f32x4 prev = lds[j];
    f32x4 cur = lds[j + kCV];
    f32x4 next = lds[j + 2 * kCV];

    int mb = m0 + k;
    mb = (mb >= 3) ? mb - 3 : mb;

    f32x4 o;
#pragma unroll
    for (int i = 0; i < kV; ++i) {
      int m = mb + i;                    // <= 5
      m = (m >= 3) ? m - 3 : m;
      m = (m >= 3) ? m - 3 : m;
      // m==0 -> identity (cur), m==1 -> read t-1 (prev), m==2 -> read t+1 (next)
      o[i] = (m == 0) ? cur[i] : ((m == 1) ? prev[i] : next[i]);
    }
    obase[j] = o;
  }
}

extern "C" void kernel_launch(void* const* d_in, const int* in_sizes, int n_in,
                              void* d_out, int out_size, void* d_ws, size_t ws_size,
                              hipStream_t stream) {
  const f32x4* in = reinterpret_cast<const f32x4*>(d_in[0]);
  f32x4* out = reinterpret_cast<f32x4*>(d_out);
  ShiftLayer_66932770341347_kernel<<<kBlocks, kThreads, 0, stream>>>(in, out);
}

// Round 6
// 174.743 us; speedup vs baseline: 1.0193x; 1.0193x over previous
//
#include <hip/hip_runtime.h>

// ShiftLayer: out[b,t,c] = in[b, t+off[c], c], off per c%3 = {0: identity, 1: t-1, 2: t+1},
// zero padding at t boundaries. B=8, L=8192, C=384 (divisible by 3), fp32 in/out.
//
// v7: persistent grid-stride + manual 2-stage pipeline. Ledger: request count
// (v6), read amplification (v5), VALU, LDS all exonerated; every one-shot-wave
// variant sits at 48-66us / ~3 TB/s with idle pipes. Remaining mechanism: each
// wave pays full load latency once, stores, retires (wave churn). Here 2048
// blocks (8/CU) stay resident for 12 iterations each; iteration k+1's 3 loads
// are issued BEFORE iteration k is consumed, so the compiler emits counted
// s_waitcnt vmcnt(3) and each wave always has ~3-6 loads in flight with no
// launch/drain gaps -- the same shape as the 6.29 TB/s m13 copy bench.
// Incremental index math (stride = +5461 rows, +32 vectors, +2 mod 3): no
// per-iteration divides. Pipeline regs statically indexed via full unroll.

constexpr int kB = 8;
constexpr int kL = 8192;
constexpr int kC = 384;
constexpr int kV = 4;                     // fp32 elements per 16B vector
constexpr int kCV = kC / kV;              // 96 vectors per (b,t) row
constexpr int kThreads = 256;
constexpr int kBlocks = 2048;             // 8 per CU -> 32 waves/CU resident
constexpr int kTotalV = kB * kL * kCV;    // 6,291,456 vectors
constexpr int kStride = kBlocks * kThreads;          // 524,288
constexpr int kIter = kTotalV / kStride;             // 12 (exact)
constexpr int kQStep = kStride / kCV;                // 5461
constexpr int kVStep = kStride % kCV;                // 32

typedef __attribute__((ext_vector_type(4))) float f32x4;

__global__ __launch_bounds__(256) void ShiftLayer_66932770341347_kernel(
    const f32x4* __restrict__ in, f32x4* __restrict__ out) {
  const f32x4 zero = {0.f, 0.f, 0.f, 0.f};

  int idx = blockIdx.x * kThreads + threadIdx.x;  // global vector index, iter 0

  // One-time decomposition; thereafter incremental.
  int q = idx / kCV;            // row index = b*kL + t
  int v = idx - q * kCV;        // vector column within row
  int t = q & (kL - 1);         // time index (kL power of 2)
  int m0 = v % 3;               // select phase; (v+j)%3 drives the mux

  // 2-stage pipeline state (statically indexed: loop is fully unrolled).
  f32x4 rp[2], rc[2], rn[2];
  int tS[2], oS[2], mS[2];

  // Prologue: issue iteration 0's 3 loads (clamped addresses at the t edges;
  // values fixed to zero at consume time).
  {
    int pi = (t == 0) ? idx : idx - kCV;
    int ni = (t == kL - 1) ? idx : idx + kCV;
    rp[0] = in[pi];
    rc[0] = in[idx];
    rn[0] = in[ni];
    tS[0] = t; oS[0] = idx; mS[0] = m0;
  }

#pragma unroll
  for (int k = 0; k < kIter; ++k) {
    const int cur = k & 1, nxt = cur ^ 1;

    if (k + 1 < kIter) {
      // Advance state and issue iteration k+1's loads BEFORE consuming k.
      idx += kStride;
      v += kVStep;
      int carry = (v >= kCV) ? 1 : 0;
      v -= carry ? kCV : 0;
      q += kQStep + carry;
      t = q & (kL - 1);
      m0 += 2;                          // kStride % 3 == 2
      m0 = (m0 >= 3) ? m0 - 3 : m0;

      int pi = (t == 0) ? idx : idx - kCV;
      int ni = (t == kL - 1) ? idx : idx + kCV;
      rp[nxt] = in[pi];
      rc[nxt] = in[idx];
      rn[nxt] = in[ni];
      tS[nxt] = t; oS[nxt] = idx; mS[nxt] = m0;
    }

    // Consume iteration k (waits only on k's loads: counted vmcnt).
    f32x4 P = (tS[cur] == 0) ? zero : rp[cur];
    f32x4 C = rc[cur];
    f32x4 N = (tS[cur] == kL - 1) ? zero : rn[cur];

    int mb = mS[cur];
    f32x4 o;
#pragma unroll
    for (int j = 0; j < kV; ++j) {
      int m = mb + j;                   // <= 5
      m = (m >= 3) ? m - 3 : m;
      m = (m >= 3) ? m - 3 : m;
      // m==0 -> identity (cur), m==1 -> read t-1 (prev), m==2 -> read t+1 (next)
      o[j] = (m == 0) ? C[j] : ((m == 1) ? P[j] : N[j]);
    }
    out[oS[cur]] = o;
  }
}

extern "C" void kernel_launch(void* const* d_in, const int* in_sizes, int n_in,
                              void* d_out, int out_size, void* d_ws, size_t ws_size,
                              hipStream_t stream) {
  const f32x4* in = reinterpret_cast<const f32x4*>(d_in[0]);
  f32x4* out = reinterpret_cast<f32x4*>(d_out);
  ShiftLayer_66932770341347_kernel<<<kBlocks, kThreads, 0, stream>>>(in, out);
}